// Round 16
// baseline (239.355 us; speedup 1.0000x reference)
//
#include <hip/hip_runtime.h>
#include <hip/hip_bf16.h>

typedef __attribute__((ext_vector_type(8))) short short8;
typedef __attribute__((ext_vector_type(4))) float f32x4;

#define EMB   1024
#define DFF   4096
#define S_LEN 2048
#define NB    2
#define MTOT  (NB * S_LEN)   // 4096
#define HEADS 16
#define HDIM  64
#define QKN   2048           // qkv buffer holds Q,K only: [4096][2048]

__device__ __forceinline__ float bf2f(unsigned short u) {
  return __uint_as_float(((unsigned int)u) << 16);
}
__device__ __forceinline__ unsigned short f2bf(float f) {
  unsigned int x = __float_as_uint(f);
  unsigned int r = (x + 0x7fffu + ((x >> 16) & 1u)) >> 16;  // RN
  return (unsigned short)r;
}
// pack 2 fp32 -> 2 bf16 in one dword (lo = a, hi = b)
__device__ __forceinline__ unsigned int cvtpk(float a, float b) {
  unsigned int r;
  asm("v_cvt_pk_bf16_f32 %0, %1, %2" : "=v"(r) : "v"(a), "v"(b));
  return r;
}

// async global->LDS, 16B per lane; lptr must be wave-uniform (HW adds lane*16)
__device__ __forceinline__ void gl_lds16(const unsigned short* g, unsigned short* l) {
  __builtin_amdgcn_global_load_lds(
      (const __attribute__((address_space(1))) unsigned int*)g,
      (__attribute__((address_space(3))) unsigned int*)l, 16, 0, 0);
}

__device__ __forceinline__ float gelu_tanh_f(float v) {
  float u = v + 0.044715f * v * v * v;
  float t = tanhf(0.7978845608028654f * u);
  return 0.5f * v * (1.0f + t);
}

// ---------------------------------------------------------------------------
// All 6 weight transposes fp32 [K,N] -> bf16 [N,K] in ONE launch.
// ---------------------------------------------------------------------------
__global__ __launch_bounds__(256) void fused_transpose(
    const float* __restrict__ Wq, const float* __restrict__ Wk,
    const float* __restrict__ Wv, const float* __restrict__ Wo,
    const float* __restrict__ W1, const float* __restrict__ W2,
    unsigned short* __restrict__ wtQ, unsigned short* __restrict__ wtK,
    unsigned short* __restrict__ wtV, unsigned short* __restrict__ wtO,
    unsigned short* __restrict__ wtW1, unsigned short* __restrict__ wtW2)
{
  __shared__ float t[64][33];
  const int bid = (int)blockIdx.x;
  const float* W; unsigned short* Wt; int K, N, local;
  if (bid < 2048) {
    const int sel = bid >> 9; local = bid & 511; K = 1024; N = 1024;
    W  = sel == 0 ? Wq  : sel == 1 ? Wk  : sel == 2 ? Wv  : Wo;
    Wt = sel == 0 ? wtQ : sel == 1 ? wtK : sel == 2 ? wtV : wtO;
  } else if (bid < 4096) {
    local = bid - 2048; K = 1024; N = 4096; W = W1; Wt = wtW1;
  } else {
    local = bid - 4096; K = 4096; N = 1024; W = W2; Wt = wtW2;
  }
  const int nbx = N >> 5;
  const int n0 = (local % nbx) * 32, k0 = (local / nbx) * 64;
  const int tx = threadIdx.x, ty = threadIdx.y;
#pragma unroll
  for (int i = 0; i < 8; ++i) {
    const int kr = i * 8 + ty;
    t[kr][tx] = W[(size_t)(k0 + kr) * N + n0 + tx];
  }
  __syncthreads();
#pragma unroll
  for (int i = 0; i < 4; ++i) {
    const int r = ty + i * 8;   // n-row within tile
    const unsigned int u = cvtpk(t[2 * tx][r], t[2 * tx + 1][r]);
    *(unsigned int*)(&Wt[(size_t)(n0 + r) * K + k0 + 2 * tx]) = u;
  }
}

// ---------------------------------------------------------------------------
// LayerNorm: fp32 [rows,1024] -> bf16 [rows,1024].  block 256, grid rows.
// ---------------------------------------------------------------------------
__global__ __launch_bounds__(256) void ln_kernel(
    const float* __restrict__ X, const float* __restrict__ g,
    const float* __restrict__ sh, unsigned short* __restrict__ H)
{
  const int row = blockIdx.x, t = threadIdx.x;
  const float* xr = X + (size_t)row * EMB;
  float4 v = *(const float4*)(xr + t * 4);
  float s  = v.x + v.y + v.z + v.w;
  float ss = v.x * v.x + v.y * v.y + v.z * v.z + v.w * v.w;
#pragma unroll
  for (int off = 32; off > 0; off >>= 1) {
    s  += __shfl_xor(s, off);
    ss += __shfl_xor(ss, off);
  }
  __shared__ float rs[4], rss[4];
  const int wid = t >> 6;
  if ((t & 63) == 0) { rs[wid] = s; rss[wid] = ss; }
  __syncthreads();
  s  = rs[0] + rs[1] + rs[2] + rs[3];
  ss = rss[0] + rss[1] + rss[2] + rss[3];
  const float mean = s * (1.f / EMB);
  const float var  = ss * (1.f / EMB) - mean * mean;
  const float rstd = rsqrtf(var + 1e-5f);
  float4 gv = *(const float4*)(g + t * 4);
  float4 sv = *(const float4*)(sh + t * 4);
  ushort4 o;
  o.x = f2bf((v.x - mean) * rstd * gv.x + sv.x);
  o.y = f2bf((v.y - mean) * rstd * gv.y + sv.y);
  o.z = f2bf((v.z - mean) * rstd * gv.z + sv.z);
  o.w = f2bf((v.w - mean) * rstd * gv.w + sv.w);
  *(ushort4*)(H + (size_t)row * EMB + t * 4) = o;
}

// ---------------------------------------------------------------------------
// GEMM  C[M,N] = A[M,Kld] * Bt[N,Kld]^T  (2-phase counted-vmcnt family)
// BM=128, template BN/BKT/NBUF.  4 waves, XCD swizzle, swizzled LDS.
// Occupancy rules (measured r9/r12): keep >=2 blocks/CU; NBUF=3 only when
// it does NOT reduce blocks/CU (72KB @ 2 blocks/CU is fine, 160/2=80KB).
// MODE 0 (fused QKV): c<1024 -> qkv Q (pre-scaled 0.125*log2e); 1024<=c<2048
//        -> qkv K; c>=2048 -> V written TRANSPOSED into vt[(b,h),d,s].
// MODE 1: outf = acc + bias[c] + resf
// MODE 2: outb = gelu(acc + bias[c])
// MODE 3: outf = acc + bias[c] + resf
// ---------------------------------------------------------------------------
template <int MODE, int BN, int BKT, int NBUF>
__global__ __launch_bounds__(256, 2) void gemm_gl(
    const unsigned short* __restrict__ A, const unsigned short* __restrict__ Bt,
    int M, int N, int Kloop, int Kld, int nbx,
    const float* __restrict__ bias, const float* __restrict__ resf,
    float* __restrict__ outf, unsigned short* __restrict__ outb,
    unsigned short* __restrict__ vt)
{
  constexpr int NFRAG = BN / 32;
  constexpr int KK    = BKT / 32;
  constexpr int ACH   = 128 * BKT / 512;
  constexpr int BCH   = BN  * BKT / 512;
  __shared__ unsigned short As[NBUF][128 * BKT];
  __shared__ unsigned short Bs[NBUF][BN * BKT];

  const int tid = threadIdx.x;
  const int lane = tid & 63, wid = tid >> 6;
  const int nwg = (int)gridDim.x;
  const int cpx = nwg >> 3;
  const int bid = (int)blockIdx.x;
  const int swz = (bid & 7) * cpx + (bid >> 3);
  const int by = swz / nbx;
  const int bx = swz - by * nbx;
  const int m0 = by * 128, n0 = bx * BN;
  const int wr = wid >> 1, wc = wid & 1;
  const int l16 = lane & 15, kg = lane >> 4;

  int sr, scs;
  if constexpr (BKT == 32) {
    sr  = lane >> 2;
    scs = ((lane & 3) ^ ((lane >> 3) & 3)) * 8;
  } else {
    sr  = lane >> 3;
    scs = ((lane & 7) ^ (lane >> 3)) * 8;
  }
  const int rx = (BKT == 32) ? ((l16 >> 1) & 3) : (l16 & 7);

  const unsigned short* Abase = A + (size_t)m0 * Kld;
  const unsigned short* Bbase = Bt + (size_t)n0 * Kld;

  f32x4 acc[4][NFRAG];
#pragma unroll
  for (int i = 0; i < 4; ++i)
#pragma unroll
    for (int j = 0; j < NFRAG; ++j) acc[i][j] = (f32x4){0.f, 0.f, 0.f, 0.f};

  const int nt = Kloop / BKT;
  constexpr int RPC = (BKT == 32) ? 16 : 8;

#define STAGE(buf, t)                                                          \
  do {                                                                         \
    const int k0_ = (t) * BKT;                                                 \
    _Pragma("unroll")                                                          \
    for (int i_ = 0; i_ < ACH / 4; ++i_) {                                     \
      const int chunk_ = wid * (ACH / 4) + i_;                                 \
      gl_lds16(Abase + (size_t)(chunk_ * RPC + sr) * Kld + k0_ + scs,          \
               &As[buf][0] + chunk_ * 512);                                    \
    }                                                                          \
    _Pragma("unroll")                                                          \
    for (int i_ = 0; i_ < BCH / 4; ++i_) {                                     \
      const int chunk_ = wid * (BCH / 4) + i_;                                 \
      gl_lds16(Bbase + (size_t)(chunk_ * RPC + sr) * Kld + k0_ + scs,          \
               &Bs[buf][0] + chunk_ * 512);                                    \
    }                                                                          \
  } while (0)

#define VM_WAIT()                                                              \
  do {                                                                         \
    constexpr int W_ = ((ACH + BCH) / 4) * (NBUF - 1);                         \
    if constexpr (W_ == 3)      asm volatile("s_waitcnt vmcnt(3)" ::: "memory"); \
    else if constexpr (W_ == 4) asm volatile("s_waitcnt vmcnt(4)" ::: "memory"); \
    else if constexpr (W_ == 6) asm volatile("s_waitcnt vmcnt(6)" ::: "memory"); \
    else if constexpr (W_ == 8) asm volatile("s_waitcnt vmcnt(8)" ::: "memory"); \
    else                        asm volatile("s_waitcnt vmcnt(12)" ::: "memory"); \
  } while (0)

  STAGE(0, 0);
  STAGE(1, 1);
  if constexpr (NBUF == 3) STAGE(2, 2);
  VM_WAIT();
  __builtin_amdgcn_s_barrier();

  int b = 0;
  for (int t = 0; t < nt; ++t) {
    short8 af[4][KK], bfr[NFRAG][KK];
#pragma unroll
    for (int i = 0; i < 4; ++i)
#pragma unroll
      for (int kk = 0; kk < KK; ++kk)
        af[i][kk] = *(const short8*)(
            &As[b][(wr * 64 + i * 16 + l16) * BKT + ((kg + kk * 4) ^ rx) * 8]);
#pragma unroll
    for (int j = 0; j < NFRAG; ++j)
#pragma unroll
      for (int kk = 0; kk < KK; ++kk)
        bfr[j][kk] = *(const short8*)(
            &Bs[b][(wc * (BN / 2) + j * 16 + l16) * BKT + ((kg + kk * 4) ^ rx) * 8]);
#pragma unroll
    for (int kk = 0; kk < KK; ++kk)
#pragma unroll
      for (int i = 0; i < 4; ++i)
#pragma unroll
        for (int j = 0; j < NFRAG; ++j)
          acc[i][j] = __builtin_amdgcn_mfma_f32_16x16x32_bf16(af[i][kk], bfr[j][kk], acc[i][j], 0, 0, 0);
    asm volatile("s_waitcnt lgkmcnt(0)" ::: "memory");
    __builtin_amdgcn_s_barrier();
    if (t + NBUF < nt) {
      STAGE(b, t + NBUF);
      VM_WAIT();
    } else {
      asm volatile("s_waitcnt vmcnt(0)" ::: "memory");
    }
    __builtin_amdgcn_s_barrier();
    if constexpr (NBUF == 2) b ^= 1;
    else                     b = (b == 2) ? 0 : b + 1;
  }
#undef STAGE
#undef VM_WAIT

#pragma unroll
  for (int i = 0; i < 4; ++i) {
#pragma unroll
    for (int j = 0; j < NFRAG; ++j) {
      const int c = n0 + wc * (BN / 2) + j * 16 + l16;
      if constexpr (MODE == 0) {
        if (c >= 2048) {
          const int row0 = m0 + wr * 64 + i * 16 + kg * 4;
          const int dcol = c - 2048;
          ushort4 w4;
          w4.x = f2bf(acc[i][j][0]); w4.y = f2bf(acc[i][j][1]);
          w4.z = f2bf(acc[i][j][2]); w4.w = f2bf(acc[i][j][3]);
          *(ushort4*)(&vt[((size_t)((row0 >> 11) * 16 + (dcol >> 6)) * 64 +
                           (dcol & 63)) * 2048 + (row0 & 2047)]) = w4;
        } else {
          const float sc = (c < 1024) ? 0.18033688011112042f : 1.0f;
#pragma unroll
          for (int r = 0; r < 4; ++r) {
            const int row = m0 + wr * 64 + i * 16 + kg * 4 + r;
            outb[(size_t)row * QKN + c] = f2bf(acc[i][j][r] * sc);
          }
        }
      } else {
#pragma unroll
        for (int r = 0; r < 4; ++r) {
          const int row = m0 + wr * 64 + i * 16 + kg * 4 + r;
          const size_t idx = (size_t)row * N + c;
          float v = acc[i][j][r];
          if constexpr (MODE == 1) {
            outf[idx] = v + bias[c] + resf[idx];
          } else if constexpr (MODE == 2) {
            outb[idx] = f2bf(gelu_tanh_f(v + bias[c]));
          } else {
            outf[idx] = v + bias[c] + resf[idx];
          }
        }
      }
    }
  }
}

// ---------------------------------------------------------------------------
// MFMA causal flash attention, swapped-operand, pair-balanced, XCD-swizzled,
// KVBLK=128 (halved barriers/bookkeeping vs 64; 64KB LDS -> 2 blocks/CU).
// ---------------------------------------------------------------------------
__global__ __launch_bounds__(256) void attn_mfma(
    const unsigned short* __restrict__ qkv, const unsigned short* __restrict__ Vt,
    unsigned short* __restrict__ ctx)
{
  __shared__ unsigned short Ks[128][64];
  __shared__ unsigned short Vs[64][128];   // [d][key]
  __shared__ unsigned short Ps[4][2][16][128];

  const int tid  = threadIdx.x;
  const int lane = tid & 63, wv = tid >> 6;
  const int l16  = lane & 15, kg = lane >> 4;
  const int bid  = (int)blockIdx.x;
  const int swz  = (bid & 7) * 64 + (bid >> 3);
  const int pair = swz & 15;
  const int bh   = swz >> 4;
  const int b    = bh >> 4, h = bh & 15;
  const int qtg0 = pair;        // light q-tile (64 rows)
  const int qtg1 = 31 - pair;   // heavy q-tile

  const size_t qbase  = ((size_t)b * S_LEN) * QKN + h * HDIM;
  const size_t kbase  = qbase + 1024;
  const size_t vtbase = ((size_t)bh * HDIM) * S_LEN;
  const size_t cbase  = ((size_t)b * S_LEN) * EMB + h * HDIM;

  short8 qf[2][2];
#pragma unroll
  for (int g = 0; g < 2; ++g) {
    const int qt = g ? qtg1 : qtg0;
    const unsigned short* qrow =
        qkv + qbase + (size_t)(qt * 64 + wv * 16 + l16) * QKN;
    qf[g][0] = *(const short8*)(qrow + kg * 8);
    qf[g][1] = *(const short8*)(qrow + 32 + kg * 8);
  }

  f32x4 o[2][4];
#pragma unroll
  for (int g = 0; g < 2; ++g)
#pragma unroll
    for (int dt = 0; dt < 4; ++dt) o[g][dt] = (f32x4){0.f, 0.f, 0.f, 0.f};
  float m[2] = {-1e30f, -1e30f}, l[2] = {0.f, 0.f};

  const int kr2 = tid >> 1, kh = tid & 1;
  const int ksx = kr2 & 7;
  const int vr = tid >> 2, vc = tid & 3;
  const int vsx = vr & 7;
  const int rx = l16 & 7;

  const int nkt = (qtg1 + 2) >> 1;

  const unsigned short* ksrc = qkv + kbase + (size_t)kr2 * QKN + kh * 32;
  const unsigned short* vsrc = Vt + vtbase + (size_t)vr * S_LEN + vc * 32;
  short8 kv0 = *(const short8*)(ksrc);
  short8 kv1 = *(const short8*)(ksrc + 8);
  short8 kv2 = *(const short8*)(ksrc + 16);
  short8 kv3 = *(const short8*)(ksrc + 24);
  short8 vv0 = *(const short8*)(vsrc);
  short8 vv1 = *(const short8*)(vsrc + 8);
  short8 vv2 = *(const short8*)(vsrc + 16);
  short8 vv3 = *(const short8*)(vsrc + 24);

  for (int kt = 0; kt < nkt; ++kt) {
    __syncthreads();
    *(short8*)(&Ks[kr2][((kh * 4 + 0) ^ ksx) * 8]) = kv0;
    *(short8*)(&Ks[kr2][((kh * 4 + 1) ^ ksx) * 8]) = kv1;
    *(short8*)(&Ks[kr2][((kh * 4 + 2) ^ ksx) * 8]) = kv2;
    *(short8*)(&Ks[kr2][((kh * 4 + 3) ^ ksx) * 8]) = kv3;
    *(short8*)(&Vs[vr][((vc * 4 + 0) ^ vsx) * 8]) = vv0;
    *(short8*)(&Vs[vr][((vc * 4 + 1) ^ vsx) * 8]) = vv1;
    *(short8*)(&Vs[vr][((vc * 4 + 2) ^ vsx) * 8]) = vv2;
    *(short8*)(&Vs[vr][((vc * 4 + 3) ^ vsx) * 8]) = vv3;
    __syncthreads();

    if (kt + 1 < nkt) {
      const unsigned short* kn =
          qkv + kbase + (size_t)((kt + 1) * 128 + kr2) * QKN + kh * 32;
      const unsigned short* vn =
          Vt + vtbase + (size_t)vr * S_LEN + (kt + 1) * 128 + vc * 32;
      kv0 = *(const short8*)(kn);
      kv1 = *(const short8*)(kn + 8);
      kv2 = *(const short8*)(kn + 16);
      kv3 = *(const short8*)(kn + 24);
      vv0 = *(const short8*)(vn);
      vv1 = *(const short8*)(vn + 8);
      vv2 = *(const short8*)(vn + 16);
      vv3 = *(const short8*)(vn + 24);
    }

    const bool act0 = (2 * kt <= qtg0);

    float fac[2] = {1.f, 1.f};
    bool resc[2] = {false, false};
#pragma unroll
    for (int g = 0; g < 2; ++g) {
      if (g == 0 && !act0) continue;
      const int qt = g ? qtg1 : qtg0;

      f32x4 sa[8];
      __builtin_amdgcn_s_setprio(1);
#pragma unroll
      for (int j = 0; j < 8; ++j) {
        short8 kf0 = *(const short8*)(&Ks[j * 16 + l16][(kg ^ rx) * 8]);
        short8 kf1 = *(const short8*)(&Ks[j * 16 + l16][((kg + 4) ^ rx) * 8]);
        sa[j] = (f32x4){0.f, 0.f, 0.f, 0.f};
        sa[j] = __builtin_amdgcn_mfma_f32_16x16x32_bf16(kf0, qf[g][0], sa[j], 0, 0, 0);
        sa[j] = __builtin_amdgcn_mfma_f32_16x16x32_bf16(kf1, qf[g][1], sa[j], 0, 0, 0);
      }
      __builtin_amdgcn_s_setprio(0);

      const int qloc = qt * 64 + wv * 16 + l16;
      if (kt * 128 + 127 > qt * 64 + wv * 16) {
#pragma unroll
        for (int j = 0; j < 8; ++j)
#pragma unroll
          for (int r = 0; r < 4; ++r)
            if (kt * 128 + j * 16 + kg * 4 + r > qloc) sa[j][r] = -1e30f;
      }

      float mx = fmaxf(fmaxf(sa[0][0], sa[0][1]), fmaxf(sa[0][2], sa[0][3]));
#pragma unroll
      for (int j = 1; j < 8; ++j) {
        float mj = fmaxf(fmaxf(sa[j][0], sa[j][1]), fmaxf(sa[j][2], sa[j][3]));
        mx = fmaxf(mx, mj);
      }
      mx = fmaxf(mx, __shfl_xor(mx, 16));
      mx = fmaxf(mx, __shfl_xor(mx, 32));
      if (!__all(mx - m[g] <= 8.0f)) {
        const float mn = fmaxf(m[g], mx);
        fac[g] = exp2f(m[g] - mn);
        m[g] = mn;
        resc[g] = true;
      }
      const float mcur = m[g];
      float ps = 0.f;
#pragma unroll
      for (int j = 0; j < 8; ++j) {
        float p0 = exp2f(sa[j][0] - mcur);
        float p1 = exp2f(sa[j][1] - mcur);
        float p2 = exp2f(sa[j][2] - mcur);
        float p3 = exp2f(sa[j][3] - mcur);
        sa[j][0] = p0; sa[j][1] = p1; sa[j][2] = p2; sa[j][3] = p3;
        ps += (p0 + p1) + (p2 + p3);
      }
      ps += __shfl_xor(ps, 16);
      ps += __shfl_xor(ps, 32);
      l[g] = l[g] * fac[g] + ps;

#pragma unroll
      for (int j = 0; j < 8; ++j) {
        uint2 pw;
        pw.x = cvtpk(sa[j][0], sa[j][1]);
        pw.y = cvtpk(sa[j][2], sa[j][3]);
        *(uint2*)(&Ps[wv][g][l16][((2 * j + (kg >> 1)) ^ rx) * 8 + (kg & 1) * 4]) = pw;
      }
    }

#pragma unroll
    for (int g = 0; g < 2; ++g) {
      if (resc[g]) {
#pragma unroll
        for (int dt = 0; dt < 4; ++dt)
#pragma unroll
          for (int r = 0; r < 4; ++r) o[g][dt][r] *= fac[g];
      }
    }

    short8 pf[2][4];
#pragma unroll
    for (int g = 0; g < 2; ++g) {
      if (g == 0 && !act0) continue;
#pragma unroll
      for (int s = 0; s < 4; ++s)
        pf[g][s] = *(const short8*)(&Ps[wv][g][l16][((4 * s + kg) ^ rx) * 8]);
    }
    __builtin_amdgcn_s_setprio(1);
#pragma unroll
    for (int dt = 0; dt < 4; ++dt) {
#pragma unroll
      for (int s = 0; s < 4; ++s) {
        short8 vf = *(const short8*)(&Vs[dt * 16 + l16][((4 * s + kg) ^ rx) * 8]);
#pragma unroll
        for (int g = 0; g < 2; ++g) {
          if (g == 0 && !act0) continue;
          o[g][dt] = __builtin_amdgcn_mfma_f32_16x16x32_bf16(vf, pf[g][s], o[g][dt], 0, 0, 0);
        }
      }
    }
    __builtin_amdgcn_s_setprio(0);
  }

#pragma unroll
  for (int g = 0; g < 2; ++g) {
    const int qt = g ? qtg1 : qtg0;
    const float inv = 1.0f / l[g];
    const int qrow = qt * 64 + wv * 16 + l16;
#pragma unroll
    for (int dt = 0; dt < 4; ++dt) {
      uint2 cw;
      cw.x = cvtpk(o[g][dt][0] * inv, o[g][dt][1] * inv);
      cw.y = cvtpk(o[g][dt][2] * inv, o[g][dt][3] * inv);
      *(uint2*)(&ctx[cbase + (size_t)qrow * EMB + dt * 16 + kg * 4]) = cw;
    }
  }
}

// ---------------------------------------------------------------------------
// ws layout (MB): 0-2 wtQ | 2-4 wtK | 4-6 wtV | 6-8 wtO | 8-16 wtW1 |
//   16-24 wtW2 | 24-32 h/ctx/h2 | 32-48 qkv | 56-64 Vt | 32-64 gbuf
// ---------------------------------------------------------------------------
extern "C" void kernel_launch(void* const* d_in, const int* in_sizes, int n_in,
                              void* d_out, int out_size, void* d_ws, size_t ws_size,
                              hipStream_t stream)
{
  const float* x  = (const float*)d_in[0];
  const float* Wq = (const float*)d_in[1];
  const float* Wk = (const float*)d_in[2];
  const float* Wv = (const float*)d_in[3];
  const float* Wo = (const float*)d_in[4];
  const float* bo = (const float*)d_in[5];
  const float* W1 = (const float*)d_in[6];
  const float* b1 = (const float*)d_in[7];
  const float* W2 = (const float*)d_in[8];
  const float* b2 = (const float*)d_in[9];
  const float* g1 = (const float*)d_in[10];
  const float* s1 = (const float*)d_in[11];
  const float* g2 = (const float*)d_in[12];
  const float* s2 = (const float*)d_in[13];

  float* out = (float*)d_out;
  char* ws = (char*)d_ws;
  const size_t MB = 1024 * 1024;
  unsigned short* wtQ  = (unsigned short*)(ws + 0 * MB);
  unsigned short* wtK  = (unsigned short*)(ws + 2 * MB);
  unsigned short* wtV  = (unsigned short*)(ws + 4 * MB);
  unsigned short* wtO  = (unsigned short*)(ws + 6 * MB);
  unsigned short* wtW1 = (unsigned short*)(ws + 8 * MB);
  unsigned short* wtW2 = (unsigned short*)(ws + 16 * MB);
  unsigned short* h    = (unsigned short*)(ws + 24 * MB);
  unsigned short* qkv  = (unsigned short*)(ws + 32 * MB);
  unsigned short* Vt   = (unsigned short*)(ws + 56 * MB);
  unsigned short* ctxb = h;
  unsigned short* h2   = h;
  unsigned short* gbuf = qkv;            // reuse 32..64MB after attn

  fused_transpose<<<dim3(6144), dim3(32, 8), 0, stream>>>(
      Wq, Wk, Wv, Wo, W1, W2, wtQ, wtK, wtV, wtO, wtW1, wtW2);

  ln_kernel<<<MTOT, 256, 0, stream>>>(x, g1, s1, h);

  // fused QKV: Q (pre-scaled), K -> qkv[4096,2048]; V -> Vt transposed
  gemm_gl<0, 128, 32, 2><<<dim3(24 * 32), 256, 0, stream>>>(
      h, wtQ, MTOT, 3072, 1024, 1024, 24, nullptr, nullptr, nullptr, qkv, Vt);

  attn_mfma<<<dim3(512), 256, 0, stream>>>(qkv, Vt, ctxb);

  // x_attn = x + ctx@Wo + bo.  512 blocks (2/CU), BKT=64, NBUF=3 (72KB).
  gemm_gl<1, 64, 64, 3><<<dim3(16 * 32), 256, 0, stream>>>(
      ctxb, wtO, MTOT, 1024, 1024, 1024, 16, bo, x, out, nullptr, nullptr);

  ln_kernel<<<MTOT, 256, 0, stream>>>(out, g2, s2, h2);

  // W1: 2-phase 128x128 (measured best: 58.9us), 1024 blocks = 4/CU.
  gemm_gl<2, 128, 32, 2><<<dim3(32 * 32), 256, 0, stream>>>(
      h2, wtW1, MTOT, DFF, 1024, 1024, 32, b1, nullptr, nullptr, gbuf, nullptr);

  // out = x_attn + gbuf@W2 + b2.  512 blocks (2/CU), BKT=64, NBUF=3 (72KB).
  gemm_gl<3, 64, 64, 3><<<dim3(16 * 32), 256, 0, stream>>>(
      gbuf, wtW2, MTOT, 1024, DFF, DFF, 16, b2, out, out, nullptr, nullptr);
}

// Round 17
// 235.269 us; speedup vs baseline: 1.0174x; 1.0174x over previous
//
#include <hip/hip_runtime.h>
#include <hip/hip_bf16.h>

typedef __attribute__((ext_vector_type(8))) short short8;
typedef __attribute__((ext_vector_type(4))) float f32x4;

#define EMB   1024
#define DFF   4096
#define S_LEN 2048
#define NB    2
#define MTOT  (NB * S_LEN)   // 4096
#define HEADS 16
#define HDIM  64
#define QKN   2048           // qkv buffer holds Q,K only: [4096][2048]

__device__ __forceinline__ float bf2f(unsigned short u) {
  return __uint_as_float(((unsigned int)u) << 16);
}
__device__ __forceinline__ unsigned short f2bf(float f) {
  unsigned int x = __float_as_uint(f);
  unsigned int r = (x + 0x7fffu + ((x >> 16) & 1u)) >> 16;  // RN
  return (unsigned short)r;
}
// pack 2 fp32 -> 2 bf16 in one dword (lo = a, hi = b)
__device__ __forceinline__ unsigned int cvtpk(float a, float b) {
  unsigned int r;
  asm("v_cvt_pk_bf16_f32 %0, %1, %2" : "=v"(r) : "v"(a), "v"(b));
  return r;
}

// async global->LDS, 16B per lane; lptr must be wave-uniform (HW adds lane*16)
__device__ __forceinline__ void gl_lds16(const unsigned short* g, unsigned short* l) {
  __builtin_amdgcn_global_load_lds(
      (const __attribute__((address_space(1))) unsigned int*)g,
      (__attribute__((address_space(3))) unsigned int*)l, 16, 0, 0);
}

__device__ __forceinline__ float gelu_tanh_f(float v) {
  float u = v + 0.044715f * v * v * v;
  float t = tanhf(0.7978845608028654f * u);
  return 0.5f * v * (1.0f + t);
}

// ---------------------------------------------------------------------------
// All 6 weight transposes fp32 [K,N] -> bf16 [N,K] in ONE launch.
// ---------------------------------------------------------------------------
__global__ __launch_bounds__(256) void fused_transpose(
    const float* __restrict__ Wq, const float* __restrict__ Wk,
    const float* __restrict__ Wv, const float* __restrict__ Wo,
    const float* __restrict__ W1, const float* __restrict__ W2,
    unsigned short* __restrict__ wtQ, unsigned short* __restrict__ wtK,
    unsigned short* __restrict__ wtV, unsigned short* __restrict__ wtO,
    unsigned short* __restrict__ wtW1, unsigned short* __restrict__ wtW2)
{
  __shared__ float t[64][33];
  const int bid = (int)blockIdx.x;
  const float* W; unsigned short* Wt; int K, N, local;
  if (bid < 2048) {
    const int sel = bid >> 9; local = bid & 511; K = 1024; N = 1024;
    W  = sel == 0 ? Wq  : sel == 1 ? Wk  : sel == 2 ? Wv  : Wo;
    Wt = sel == 0 ? wtQ : sel == 1 ? wtK : sel == 2 ? wtV : wtO;
  } else if (bid < 4096) {
    local = bid - 2048; K = 1024; N = 4096; W = W1; Wt = wtW1;
  } else {
    local = bid - 4096; K = 4096; N = 1024; W = W2; Wt = wtW2;
  }
  const int nbx = N >> 5;
  const int n0 = (local % nbx) * 32, k0 = (local / nbx) * 64;
  const int tx = threadIdx.x, ty = threadIdx.y;
#pragma unroll
  for (int i = 0; i < 8; ++i) {
    const int kr = i * 8 + ty;
    t[kr][tx] = W[(size_t)(k0 + kr) * N + n0 + tx];
  }
  __syncthreads();
#pragma unroll
  for (int i = 0; i < 4; ++i) {
    const int r = ty + i * 8;   // n-row within tile
    const unsigned int u = cvtpk(t[2 * tx][r], t[2 * tx + 1][r]);
    *(unsigned int*)(&Wt[(size_t)(n0 + r) * K + k0 + 2 * tx]) = u;
  }
}

// ---------------------------------------------------------------------------
// LayerNorm: fp32 [rows,1024] -> bf16 [rows,1024].  block 256, grid rows.
// ---------------------------------------------------------------------------
__global__ __launch_bounds__(256) void ln_kernel(
    const float* __restrict__ X, const float* __restrict__ g,
    const float* __restrict__ sh, unsigned short* __restrict__ H)
{
  const int row = blockIdx.x, t = threadIdx.x;
  const float* xr = X + (size_t)row * EMB;
  float4 v = *(const float4*)(xr + t * 4);
  float s  = v.x + v.y + v.z + v.w;
  float ss = v.x * v.x + v.y * v.y + v.z * v.z + v.w * v.w;
#pragma unroll
  for (int off = 32; off > 0; off >>= 1) {
    s  += __shfl_xor(s, off);
    ss += __shfl_xor(ss, off);
  }
  __shared__ float rs[4], rss[4];
  const int wid = t >> 6;
  if ((t & 63) == 0) { rs[wid] = s; rss[wid] = ss; }
  __syncthreads();
  s  = rs[0] + rs[1] + rs[2] + rs[3];
  ss = rss[0] + rss[1] + rss[2] + rss[3];
  const float mean = s * (1.f / EMB);
  const float var  = ss * (1.f / EMB) - mean * mean;
  const float rstd = rsqrtf(var + 1e-5f);
  float4 gv = *(const float4*)(g + t * 4);
  float4 sv = *(const float4*)(sh + t * 4);
  ushort4 o;
  o.x = f2bf((v.x - mean) * rstd * gv.x + sv.x);
  o.y = f2bf((v.y - mean) * rstd * gv.y + sv.y);
  o.z = f2bf((v.z - mean) * rstd * gv.z + sv.z);
  o.w = f2bf((v.w - mean) * rstd * gv.w + sv.w);
  *(ushort4*)(H + (size_t)row * EMB + t * 4) = o;
}

// ---------------------------------------------------------------------------
// 8-phase 256x256 GEMM for W1 (M=N=4096, K=1024): faithful T3+T4 port.
// 8 waves (2Mx4N), BK=64, 16 K-tile groups, 4 phases/group:
//   phase mp: {ds_read A m-pair (B once/group, held in regs);
//              issue ONE half-tile stage; barrier; lgkm(0);
//              setprio(1); 16 MFMA; setprio(0); barrier}
// Stage schedule (slot recycling, verified by death/stage argument):
//   group t (reads buf b=t&1): ph0: A-half0(t+1)->As[b^1]  (t>=1)
//                              ph1: A-half1(t+1)->As[b^1]  (t>=1)
//                              ph2: B-half0(t+2)->Bs[b]
//                              ph3: B-half1(t+2)->Bs[b]
//   (B slots of buf b die after ph0's 2nd barrier since B is register-held;
//    A slots of As[b^1] died at group t-1 ph3's 2nd barrier.)
// Counted vmcnt(4) ONCE per group (before ph3's 2nd barrier): queue =
// [B(t+1):4][A(t+1):4][B(t+2):4]; leave newest 4 -> everything needed by
// group t+1 has landed, block-wide via the barrier.  Never drains mid-loop.
// LDS 128KB (1 block/CU, 2 waves/SIMD).  Epilogue: gelu(acc+bias) -> bf16.
// ---------------------------------------------------------------------------
__global__ __launch_bounds__(512, 2) void gemm8p(
    const unsigned short* __restrict__ A, const unsigned short* __restrict__ Bt,
    const float* __restrict__ bias, unsigned short* __restrict__ outb)
{
  __shared__ unsigned short As[2][256 * 64];
  __shared__ unsigned short Bs[2][256 * 64];

  const int tid = threadIdx.x;
  const int lane = tid & 63, wid = tid >> 6;
  const int bid = (int)blockIdx.x;
  const int swz = (bid & 7) * 32 + (bid >> 3);   // XCD-chunked, 256 blocks
  const int by = swz >> 4, bx = swz & 15;
  const int m0 = by * 256, n0 = bx * 256;
  const int wr = wid >> 2, wc = wid & 3;
  const int l16 = lane & 15, kg = lane >> 4;

  const int sr  = lane >> 3;                     // 8-row x 64-col 1KB chunks
  const int scs = ((lane & 7) ^ (lane >> 3)) * 8;
  const int rx  = l16 & 7;

  const unsigned short* Ab = A + (size_t)m0 * 1024;
  const unsigned short* Bb = Bt + (size_t)n0 * 1024;

  f32x4 acc[8][4];
#pragma unroll
  for (int i = 0; i < 8; ++i)
#pragma unroll
    for (int j = 0; j < 4; ++j) acc[i][j] = (f32x4){0.f, 0.f, 0.f, 0.f};

// stage one 128-row half (16 chunks of 8 rows; 2 chunks/wave)
#define STGH(ldsdst, gb, grow0, kt_)                                           \
  do {                                                                         \
    _Pragma("unroll")                                                          \
    for (int i_ = 0; i_ < 2; ++i_) {                                           \
      const int c_ = wid * 2 + i_;                                             \
      gl_lds16((gb) + (size_t)((grow0) + c_ * 8 + sr) * 1024 + (kt_) * 64 + scs, \
               (ldsdst) + c_ * 512);                                           \
    }                                                                          \
  } while (0)

#define PHASE(mp, STAGE_STMT, TAIL_STMT)                                       \
  do {                                                                         \
    short8 af[2][2];                                                           \
    _Pragma("unroll")                                                          \
    for (int i = 0; i < 2; ++i)                                                \
      _Pragma("unroll")                                                        \
      for (int kk = 0; kk < 2; ++kk)                                           \
        af[i][kk] = *(const short8*)(                                          \
            &As[b][(wr * 128 + ((mp) * 2 + i) * 16 + l16) * 64 +               \
                   ((kg + kk * 4) ^ rx) * 8]);                                 \
    STAGE_STMT;                                                                \
    __builtin_amdgcn_s_barrier();                                              \
    asm volatile("s_waitcnt lgkmcnt(0)" ::: "memory");                         \
    __builtin_amdgcn_s_setprio(1);                                             \
    _Pragma("unroll")                                                          \
    for (int kk = 0; kk < 2; ++kk)                                             \
      _Pragma("unroll")                                                        \
      for (int j = 0; j < 4; ++j)                                              \
        _Pragma("unroll")                                                      \
        for (int i = 0; i < 2; ++i)                                            \
          acc[(mp) * 2 + i][j] = __builtin_amdgcn_mfma_f32_16x16x32_bf16(      \
              af[i][kk], bf[j][kk], acc[(mp) * 2 + i][j], 0, 0, 0);            \
    __builtin_amdgcn_s_setprio(0);                                             \
    TAIL_STMT;                                                                 \
    __builtin_amdgcn_s_barrier();                                              \
  } while (0)

  // prologue: K-tiles 0,1 fully staged; wait for tile 0 (first 8 loads)
  STGH(&As[0][0], Ab, 0, 0);   STGH(&As[0][128 * 64], Ab, 128, 0);
  STGH(&Bs[0][0], Bb, 0, 0);   STGH(&Bs[0][128 * 64], Bb, 128, 0);
  STGH(&As[1][0], Ab, 0, 1);   STGH(&As[1][128 * 64], Ab, 128, 1);
  STGH(&Bs[1][0], Bb, 0, 1);   STGH(&Bs[1][128 * 64], Bb, 128, 1);
  asm volatile("s_waitcnt vmcnt(8)" ::: "memory");
  __builtin_amdgcn_s_barrier();

  const int nt = 16;
  for (int t = 0; t < nt; ++t) {
    const int b = t & 1;
    short8 bf[4][2];                 // B fragments for the whole K-tile
#pragma unroll
    for (int j = 0; j < 4; ++j)
#pragma unroll
      for (int kk = 0; kk < 2; ++kk)
        bf[j][kk] = *(const short8*)(
            &Bs[b][(wc * 64 + j * 16 + l16) * 64 + ((kg + kk * 4) ^ rx) * 8]);

    PHASE(0, if (t >= 1 && t + 1 < nt) STGH(&As[b ^ 1][0], Ab, 0, t + 1), );
    PHASE(1, if (t >= 1 && t + 1 < nt) STGH(&As[b ^ 1][128 * 64], Ab, 128, t + 1), );
    PHASE(2, if (t + 2 < nt) STGH(&Bs[b][0], Bb, 0, t + 2), );
    PHASE(3, if (t + 2 < nt) STGH(&Bs[b][128 * 64], Bb, 128, t + 2),
          if (t + 2 < nt) { asm volatile("s_waitcnt vmcnt(4)" ::: "memory"); }
          else            { asm volatile("s_waitcnt vmcnt(0)" ::: "memory"); });
  }
#undef PHASE
#undef STGH

  // epilogue: gelu(acc + bias) -> bf16
#pragma unroll
  for (int i = 0; i < 8; ++i) {
#pragma unroll
    for (int j = 0; j < 4; ++j) {
      const int c = n0 + wc * 64 + j * 16 + l16;
      const float bc = bias[c];
#pragma unroll
      for (int r = 0; r < 4; ++r) {
        const int row = m0 + wr * 128 + i * 16 + kg * 4 + r;
        outb[(size_t)row * 4096 + c] = f2bf(gelu_tanh_f(acc[i][j][r] + bc));
      }
    }
  }
}

// ---------------------------------------------------------------------------
// GEMM  C[M,N] = A[M,Kld] * Bt[N,Kld]^T  (2-phase counted-vmcnt family)
// ---------------------------------------------------------------------------
template <int MODE, int BN, int BKT, int NBUF>
__global__ __launch_bounds__(256, 2) void gemm_gl(
    const unsigned short* __restrict__ A, const unsigned short* __restrict__ Bt,
    int M, int N, int Kloop, int Kld, int nbx,
    const float* __restrict__ bias, const float* __restrict__ resf,
    float* __restrict__ outf, unsigned short* __restrict__ outb,
    unsigned short* __restrict__ vt)
{
  constexpr int NFRAG = BN / 32;
  constexpr int KK    = BKT / 32;
  constexpr int ACH   = 128 * BKT / 512;
  constexpr int BCH   = BN  * BKT / 512;
  __shared__ unsigned short As[NBUF][128 * BKT];
  __shared__ unsigned short Bs[NBUF][BN * BKT];

  const int tid = threadIdx.x;
  const int lane = tid & 63, wid = tid >> 6;
  const int nwg = (int)gridDim.x;
  const int cpx = nwg >> 3;
  const int bid = (int)blockIdx.x;
  const int swz = (bid & 7) * cpx + (bid >> 3);
  const int by = swz / nbx;
  const int bx = swz - by * nbx;
  const int m0 = by * 128, n0 = bx * BN;
  const int wr = wid >> 1, wc = wid & 1;
  const int l16 = lane & 15, kg = lane >> 4;

  int sr, scs;
  if constexpr (BKT == 32) {
    sr  = lane >> 2;
    scs = ((lane & 3) ^ ((lane >> 3) & 3)) * 8;
  } else {
    sr  = lane >> 3;
    scs = ((lane & 7) ^ (lane >> 3)) * 8;
  }
  const int rx = (BKT == 32) ? ((l16 >> 1) & 3) : (l16 & 7);

  const unsigned short* Abase = A + (size_t)m0 * Kld;
  const unsigned short* Bbase = Bt + (size_t)n0 * Kld;

  f32x4 acc[4][NFRAG];
#pragma unroll
  for (int i = 0; i < 4; ++i)
#pragma unroll
    for (int j = 0; j < NFRAG; ++j) acc[i][j] = (f32x4){0.f, 0.f, 0.f, 0.f};

  const int nt = Kloop / BKT;
  constexpr int RPC = (BKT == 32) ? 16 : 8;

#define STAGE(buf, t)                                                          \
  do {                                                                         \
    const int k0_ = (t) * BKT;                                                 \
    _Pragma("unroll")                                                          \
    for (int i_ = 0; i_ < ACH / 4; ++i_) {                                     \
      const int chunk_ = wid * (ACH / 4) + i_;                                 \
      gl_lds16(Abase + (size_t)(chunk_ * RPC + sr) * Kld + k0_ + scs,          \
               &As[buf][0] + chunk_ * 512);                                    \
    }                                                                          \
    _Pragma("unroll")                                                          \
    for (int i_ = 0; i_ < BCH / 4; ++i_) {                                     \
      const int chunk_ = wid * (BCH / 4) + i_;                                 \
      gl_lds16(Bbase + (size_t)(chunk_ * RPC + sr) * Kld + k0_ + scs,          \
               &Bs[buf][0] + chunk_ * 512);                                    \
    }                                                                          \
  } while (0)

#define VM_WAIT()                                                              \
  do {                                                                         \
    constexpr int W_ = ((ACH + BCH) / 4) * (NBUF - 1);                         \
    if constexpr (W_ == 3)      asm volatile("s_waitcnt vmcnt(3)" ::: "memory"); \
    else if constexpr (W_ == 4) asm volatile("s_waitcnt vmcnt(4)" ::: "memory"); \
    else if constexpr (W_ == 6) asm volatile("s_waitcnt vmcnt(6)" ::: "memory"); \
    else if constexpr (W_ == 8) asm volatile("s_waitcnt vmcnt(8)" ::: "memory"); \
    else                        asm volatile("s_waitcnt vmcnt(12)" ::: "memory"); \
  } while (0)

  STAGE(0, 0);
  STAGE(1, 1);
  if constexpr (NBUF == 3) STAGE(2, 2);
  VM_WAIT();
  __builtin_amdgcn_s_barrier();

  int b = 0;
  for (int t = 0; t < nt; ++t) {
    short8 af[4][KK], bfr[NFRAG][KK];
#pragma unroll
    for (int i = 0; i < 4; ++i)
#pragma unroll
      for (int kk = 0; kk < KK; ++kk)
        af[i][kk] = *(const short8*)(
            &As[b][(wr * 64 + i * 16 + l16) * BKT + ((kg + kk * 4) ^ rx) * 8]);
#pragma unroll
    for (int j = 0; j < NFRAG; ++j)
#pragma unroll
      for (int kk = 0; kk < KK; ++kk)
        bfr[j][kk] = *(const short8*)(
            &Bs[b][(wc * (BN / 2) + j * 16 + l16) * BKT + ((kg + kk * 4) ^ rx) * 8]);
#pragma unroll
    for (int kk = 0; kk < KK; ++kk)
#pragma unroll
      for (int i = 0; i < 4; ++i)
#pragma unroll
        for (int j = 0; j < NFRAG; ++j)
          acc[i][j] = __builtin_amdgcn_mfma_f32_16x16x32_bf16(af[i][kk], bfr[j][kk], acc[i][j], 0, 0, 0);
    asm volatile("s_waitcnt lgkmcnt(0)" ::: "memory");
    __builtin_amdgcn_s_barrier();
    if (t + NBUF < nt) {
      STAGE(b, t + NBUF);
      VM_WAIT();
    } else {
      asm volatile("s_waitcnt vmcnt(0)" ::: "memory");
    }
    __builtin_amdgcn_s_barrier();
    if constexpr (NBUF == 2) b ^= 1;
    else                     b = (b == 2) ? 0 : b + 1;
  }
#undef STAGE
#undef VM_WAIT

#pragma unroll
  for (int i = 0; i < 4; ++i) {
#pragma unroll
    for (int j = 0; j < NFRAG; ++j) {
      const int c = n0 + wc * (BN / 2) + j * 16 + l16;
      if constexpr (MODE == 0) {
        if (c >= 2048) {
          const int row0 = m0 + wr * 64 + i * 16 + kg * 4;
          const int dcol = c - 2048;
          ushort4 w4;
          w4.x = f2bf(acc[i][j][0]); w4.y = f2bf(acc[i][j][1]);
          w4.z = f2bf(acc[i][j][2]); w4.w = f2bf(acc[i][j][3]);
          *(ushort4*)(&vt[((size_t)((row0 >> 11) * 16 + (dcol >> 6)) * 64 +
                           (dcol & 63)) * 2048 + (row0 & 2047)]) = w4;
        } else {
          const float sc = (c < 1024) ? 0.18033688011112042f : 1.0f;
#pragma unroll
          for (int r = 0; r < 4; ++r) {
            const int row = m0 + wr * 64 + i * 16 + kg * 4 + r;
            outb[(size_t)row * QKN + c] = f2bf(acc[i][j][r] * sc);
          }
        }
      } else {
#pragma unroll
        for (int r = 0; r < 4; ++r) {
          const int row = m0 + wr * 64 + i * 16 + kg * 4 + r;
          const size_t idx = (size_t)row * N + c;
          float v = acc[i][j][r];
          if constexpr (MODE == 1) {
            outf[idx] = v + bias[c] + resf[idx];
          } else if constexpr (MODE == 2) {
            outb[idx] = f2bf(gelu_tanh_f(v + bias[c]));
          } else {
            outf[idx] = v + bias[c] + resf[idx];
          }
        }
      }
    }
  }
}

// ---------------------------------------------------------------------------
// MFMA causal flash attention, swapped-operand, pair-balanced, XCD-swizzled,
// KVBLK=128.
// ---------------------------------------------------------------------------
__global__ __launch_bounds__(256) void attn_mfma(
    const unsigned short* __restrict__ qkv, const unsigned short* __restrict__ Vt,
    unsigned short* __restrict__ ctx)
{
  __shared__ unsigned short Ks[128][64];
  __shared__ unsigned short Vs[64][128];   // [d][key]
  __shared__ unsigned short Ps[4][2][16][128];

  const int tid  = threadIdx.x;
  const int lane = tid & 63, wv = tid >> 6;
  const int l16  = lane & 15, kg = lane >> 4;
  const int bid  = (int)blockIdx.x;
  const int swz  = (bid & 7) * 64 + (bid >> 3);
  const int pair = swz & 15;
  const int bh   = swz >> 4;
  const int b    = bh >> 4, h = bh & 15;
  const int qtg0 = pair;        // light q-tile (64 rows)
  const int qtg1 = 31 - pair;   // heavy q-tile

  const size_t qbase  = ((size_t)b * S_LEN) * QKN + h * HDIM;
  const size_t kbase  = qbase + 1024;
  const size_t vtbase = ((size_t)bh * HDIM) * S_LEN;
  const size_t cbase  = ((size_t)b * S_LEN) * EMB + h * HDIM;

  short8 qf[2][2];
#pragma unroll
  for (int g = 0; g < 2; ++g) {
    const int qt = g ? qtg1 : qtg0;
    const unsigned short* qrow =
        qkv + qbase + (size_t)(qt * 64 + wv * 16 + l16) * QKN;
    qf[g][0] = *(const short8*)(qrow + kg * 8);
    qf[g][1] = *(const short8*)(qrow + 32 + kg * 8);
  }

  f32x4 o[2][4];
#pragma unroll
  for (int g = 0; g < 2; ++g)
#pragma unroll
    for (int dt = 0; dt < 4; ++dt) o[g][dt] = (f32x4){0.f, 0.f, 0.f, 0.f};
  float m[2] = {-1e30f, -1e30f}, l[2] = {0.f, 0.f};

  const int kr2 = tid >> 1, kh = tid & 1;
  const int ksx = kr2 & 7;
  const int vr = tid >> 2, vc = tid & 3;
  const int vsx = vr & 7;
  const int rx = l16 & 7;

  const int nkt = (qtg1 + 2) >> 1;

  const unsigned short* ksrc = qkv + kbase + (size_t)kr2 * QKN + kh * 32;
  const unsigned short* vsrc = Vt + vtbase + (size_t)vr * S_LEN + vc * 32;
  short8 kv0 = *(const short8*)(ksrc);
  short8 kv1 = *(const short8*)(ksrc + 8);
  short8 kv2 = *(const short8*)(ksrc + 16);
  short8 kv3 = *(const short8*)(ksrc + 24);
  short8 vv0 = *(const short8*)(vsrc);
  short8 vv1 = *(const short8*)(vsrc + 8);
  short8 vv2 = *(const short8*)(vsrc + 16);
  short8 vv3 = *(const short8*)(vsrc + 24);

  for (int kt = 0; kt < nkt; ++kt) {
    __syncthreads();
    *(short8*)(&Ks[kr2][((kh * 4 + 0) ^ ksx) * 8]) = kv0;
    *(short8*)(&Ks[kr2][((kh * 4 + 1) ^ ksx) * 8]) = kv1;
    *(short8*)(&Ks[kr2][((kh * 4 + 2) ^ ksx) * 8]) = kv2;
    *(short8*)(&Ks[kr2][((kh * 4 + 3) ^ ksx) * 8]) = kv3;
    *(short8*)(&Vs[vr][((vc * 4 + 0) ^ vsx) * 8]) = vv0;
    *(short8*)(&Vs[vr][((vc * 4 + 1) ^ vsx) * 8]) = vv1;
    *(short8*)(&Vs[vr][((vc * 4 + 2) ^ vsx) * 8]) = vv2;
    *(short8*)(&Vs[vr][((vc * 4 + 3) ^ vsx) * 8]) = vv3;
    __syncthreads();

    if (kt + 1 < nkt) {
      const unsigned short* kn =
          qkv + kbase + (size_t)((kt + 1) * 128 + kr2) * QKN + kh * 32;
      const unsigned short* vn =
          Vt + vtbase + (size_t)vr * S_LEN + (kt + 1) * 128 + vc * 32;
      kv0 = *(const short8*)(kn);
      kv1 = *(const short8*)(kn + 8);
      kv2 = *(const short8*)(kn + 16);
      kv3 = *(const short8*)(kn + 24);
      vv0 = *(const short8*)(vn);
      vv1 = *(const short8*)(vn + 8);
      vv2 = *(const short8*)(vn + 16);
      vv3 = *(const short8*)(vn + 24);
    }

    const bool act0 = (2 * kt <= qtg0);

    float fac[2] = {1.f, 1.f};
    bool resc[2] = {false, false};
#pragma unroll
    for (int g = 0; g < 2; ++g) {
      if (g == 0 && !act0) continue;
      const int qt = g ? qtg1 : qtg0;

      f32x4 sa[8];
      __builtin_amdgcn_s_setprio(1);
#pragma unroll
      for (int j = 0; j < 8; ++j) {
        short8 kf0 = *(const short8*)(&Ks[j * 16 + l16][(kg ^ rx) * 8]);
        short8 kf1 = *(const short8*)(&Ks[j * 16 + l16][((kg + 4) ^ rx) * 8]);
        sa[j] = (f32x4){0.f, 0.f, 0.f, 0.f};
        sa[j] = __builtin_amdgcn_mfma_f32_16x16x32_bf16(kf0, qf[g][0], sa[j], 0, 0, 0);
        sa[j] = __builtin_amdgcn_mfma_f32_16x16x32_bf16(kf1, qf[g][1], sa[j], 0, 0, 0);
      }
      __builtin_amdgcn_s_setprio(0);

      const int qloc = qt * 64 + wv * 16 + l16;
      if (kt * 128 + 127 > qt * 64 + wv * 16) {
#pragma unroll
        for (int j = 0; j < 8; ++j)
#pragma unroll
          for (int r = 0; r < 4; ++r)
            if (kt * 128 + j * 16 + kg * 4 + r > qloc) sa[j][r] = -1e30f;
      }

      float mx = fmaxf(fmaxf(sa[0][0], sa[0][1]), fmaxf(sa[0][2], sa[0][3]));
#pragma unroll
      for (int j = 1; j < 8; ++j) {
        float mj = fmaxf(fmaxf(sa[j][0], sa[j][1]), fmaxf(sa[j][2], sa[j][3]));
        mx = fmaxf(mx, mj);
      }
      mx = fmaxf(mx, __shfl_xor(mx, 16));
      mx = fmaxf(mx, __shfl_xor(mx, 32));
      if (!__all(mx - m[g] <= 8.0f)) {
        const float mn = fmaxf(m[g], mx);
        fac[g] = exp2f(m[g] - mn);
        m[g] = mn;
        resc[g] = true;
      }
      const float mcur = m[g];
      float ps = 0.f;
#pragma unroll
      for (int j = 0; j < 8; ++j) {
        float p0 = exp2f(sa[j][0] - mcur);
        float p1 = exp2f(sa[j][1] - mcur);
        float p2 = exp2f(sa[j][2] - mcur);
        float p3 = exp2f(sa[j][3] - mcur);
        sa[j][0] = p0; sa[j][1] = p1; sa[j][2] = p2; sa[j][3] = p3;
        ps += (p0 + p1) + (p2 + p3);
      }
      ps += __shfl_xor(ps, 16);
      ps += __shfl_xor(ps, 32);
      l[g] = l[g] * fac[g] + ps;

#pragma unroll
      for (int j = 0; j < 8; ++j) {
        uint2 pw;
        pw.x = cvtpk(sa[j][0], sa[j][1]);
        pw.y = cvtpk(sa[j][2], sa[j][3]);
        *(uint2*)(&Ps[wv][g][l16][((2 * j + (kg >> 1)) ^ rx) * 8 + (kg & 1) * 4]) = pw;
      }
    }

#pragma unroll
    for (int g = 0; g < 2; ++g) {
      if (resc[g]) {
#pragma unroll
        for (int dt = 0; dt < 4; ++dt)
#pragma unroll
          for (int r = 0; r < 4; ++r) o[g][dt][r] *= fac[g];
      }
    }

    short8 pf[2][4];
#pragma unroll
    for (int g = 0; g < 2; ++g) {
      if (g == 0 && !act0) continue;
#pragma unroll
      for (int s = 0; s < 4; ++s)
        pf[g][s] = *(const short8*)(&Ps[wv][g][l16][((4 * s + kg) ^ rx) * 8]);
    }
    __builtin_amdgcn_s_setprio(1);
#pragma unroll
    for (int dt = 0; dt < 4; ++dt) {
#pragma unroll
      for (int s = 0; s < 4; ++s) {
        short8 vf = *(const short8*)(&Vs[dt * 16 + l16][((4 * s + kg) ^ rx) * 8]);
#pragma unroll
        for (int g = 0; g < 2; ++g) {
          if (g == 0 && !act0) continue;
          o[g][dt] = __builtin_amdgcn_mfma_f32_16x16x32_bf16(vf, pf[g][s], o[g][dt], 0, 0, 0);
        }
      }
    }
    __builtin_amdgcn_s_setprio(0);
  }

#pragma unroll
  for (int g = 0; g < 2; ++g) {
    const int qt = g ? qtg1 : qtg0;
    const float inv = 1.0f / l[g];
    const int qrow = qt * 64 + wv * 16 + l16;
#pragma unroll
    for (int dt = 0; dt < 4; ++dt) {
      uint2 cw;
      cw.x = cvtpk(o[g][dt][0] * inv, o[g][dt][1] * inv);
      cw.y = cvtpk(o[g][dt][2] * inv, o[g][dt][3] * inv);
      *(uint2*)(&ctx[cbase + (size_t)qrow * EMB + dt * 16 + kg * 4]) = cw;
    }
  }
}

// ---------------------------------------------------------------------------
// ws layout (MB): 0-2 wtQ | 2-4 wtK | 4-6 wtV | 6-8 wtO | 8-16 wtW1 |
//   16-24 wtW2 | 24-32 h/ctx/h2 | 32-48 qkv | 56-64 Vt | 32-64 gbuf
// ---------------------------------------------------------------------------
extern "C" void kernel_launch(void* const* d_in, const int* in_sizes, int n_in,
                              void* d_out, int out_size, void* d_ws, size_t ws_size,
                              hipStream_t stream)
{
  const float* x  = (const float*)d_in[0];
  const float* Wq = (const float*)d_in[1];
  const float* Wk = (const float*)d_in[2];
  const float* Wv = (const float*)d_in[3];
  const float* Wo = (const float*)d_in[4];
  const float* bo = (const float*)d_in[5];
  const float* W1 = (const float*)d_in[6];
  const float* b1 = (const float*)d_in[7];
  const float* W2 = (const float*)d_in[8];
  const float* b2 = (const float*)d_in[9];
  const float* g1 = (const float*)d_in[10];
  const float* s1 = (const float*)d_in[11];
  const float* g2 = (const float*)d_in[12];
  const float* s2 = (const float*)d_in[13];

  float* out = (float*)d_out;
  char* ws = (char*)d_ws;
  const size_t MB = 1024 * 1024;
  unsigned short* wtQ  = (unsigned short*)(ws + 0 * MB);
  unsigned short* wtK  = (unsigned short*)(ws + 2 * MB);
  unsigned short* wtV  = (unsigned short*)(ws + 4 * MB);
  unsigned short* wtO  = (unsigned short*)(ws + 6 * MB);
  unsigned short* wtW1 = (unsigned short*)(ws + 8 * MB);
  unsigned short* wtW2 = (unsigned short*)(ws + 16 * MB);
  unsigned short* h    = (unsigned short*)(ws + 24 * MB);
  unsigned short* qkv  = (unsigned short*)(ws + 32 * MB);
  unsigned short* Vt   = (unsigned short*)(ws + 56 * MB);
  unsigned short* ctxb = h;
  unsigned short* h2   = h;
  unsigned short* gbuf = qkv;            // reuse 32..64MB after attn

  fused_transpose<<<dim3(6144), dim3(32, 8), 0, stream>>>(
      Wq, Wk, Wv, Wo, W1, W2, wtQ, wtK, wtV, wtO, wtW1, wtW2);

  ln_kernel<<<MTOT, 256, 0, stream>>>(x, g1, s1, h);

  // fused QKV: Q (pre-scaled), K -> qkv[4096,2048]; V -> Vt transposed
  gemm_gl<0, 128, 32, 2><<<dim3(24 * 32), 256, 0, stream>>>(
      h, wtQ, MTOT, 3072, 1024, 1024, 24, nullptr, nullptr, nullptr, qkv, Vt);

  attn_mfma<<<dim3(512), 256, 0, stream>>>(qkv, Vt, ctxb);

  // x_attn = x + ctx@Wo + bo.  512 blocks (2/CU), BKT=64, NBUF=2 (r13 best).
  gemm_gl<1, 64, 64, 2><<<dim3(16 * 32), 256, 0, stream>>>(
      ctxb, wtO, MTOT, 1024, 1024, 1024, 16, bo, x, out, nullptr, nullptr);

  ln_kernel<<<MTOT, 256, 0, stream>>>(out, g2, s2, h2);

  // W1: 8-phase 256x256 (T3+T4 faithful port), 256 blocks, 8 waves.
  gemm8p<<<dim3(256), 512, 0, stream>>>(h2, wtW1, b1, gbuf);

  // out = x_attn + gbuf@W2 + b2.  512 blocks (2/CU), BKT=64, NBUF=2.
  gemm_gl<3, 64, 64, 2><<<dim3(16 * 32), 256, 0, stream>>>(
      gbuf, wtW2, MTOT, 1024, DFF, DFF, 16, b2, out, out, nullptr, nullptr);
}

// Round 18
// 232.985 us; speedup vs baseline: 1.0273x; 1.0098x over previous
//
#include <hip/hip_runtime.h>
#include <hip/hip_bf16.h>

typedef __attribute__((ext_vector_type(8))) short short8;
typedef __attribute__((ext_vector_type(4))) float f32x4;

#define EMB   1024
#define DFF   4096
#define S_LEN 2048
#define NB    2
#define MTOT  (NB * S_LEN)   // 4096
#define HEADS 16
#define HDIM  64
#define QKN   2048           // qkv buffer holds Q,K only: [4096][2048]

__device__ __forceinline__ float bf2f(unsigned short u) {
  return __uint_as_float(((unsigned int)u) << 16);
}
__device__ __forceinline__ unsigned short f2bf(float f) {
  unsigned int x = __float_as_uint(f);
  unsigned int r = (x + 0x7fffu + ((x >> 16) & 1u)) >> 16;  // RN
  return (unsigned short)r;
}
// pack 2 fp32 -> 2 bf16 in one dword (lo = a, hi = b)
__device__ __forceinline__ unsigned int cvtpk(float a, float b) {
  unsigned int r;
  asm("v_cvt_pk_bf16_f32 %0, %1, %2" : "=v"(r) : "v"(a), "v"(b));
  return r;
}

// async global->LDS, 16B per lane; lptr must be wave-uniform (HW adds lane*16)
__device__ __forceinline__ void gl_lds16(const unsigned short* g, unsigned short* l) {
  __builtin_amdgcn_global_load_lds(
      (const __attribute__((address_space(1))) unsigned int*)g,
      (__attribute__((address_space(3))) unsigned int*)l, 16, 0, 0);
}

__device__ __forceinline__ float gelu_tanh_f(float v) {
  float u = v + 0.044715f * v * v * v;
  float t = tanhf(0.7978845608028654f * u);
  return 0.5f * v * (1.0f + t);
}

// ---------------------------------------------------------------------------
// Fused: 6 weight transposes (fp32 [K,N] -> bf16 [N,K]) + LN1 in ONE launch.
// flat bid: [0,2048) Wq/Wk/Wv/Wo (512 each) | [2048,4096) W1 | [4096,6144) W2
//           [6144,10240) -> ln1 row (bid-6144)
// block 256 flat.
// ---------------------------------------------------------------------------
__global__ __launch_bounds__(256) void prep_kernel(
    const float* __restrict__ Wq, const float* __restrict__ Wk,
    const float* __restrict__ Wv, const float* __restrict__ Wo,
    const float* __restrict__ W1, const float* __restrict__ W2,
    unsigned short* __restrict__ wtQ, unsigned short* __restrict__ wtK,
    unsigned short* __restrict__ wtV, unsigned short* __restrict__ wtO,
    unsigned short* __restrict__ wtW1, unsigned short* __restrict__ wtW2,
    const float* __restrict__ X, const float* __restrict__ g1,
    const float* __restrict__ s1, unsigned short* __restrict__ H)
{
  const int bid = (int)blockIdx.x;
  const int tid = threadIdx.x;

  if (bid >= 6144) {
    // ---- LayerNorm row ----
    const int row = bid - 6144;
    const float* xr = X + (size_t)row * EMB;
    float4 v = *(const float4*)(xr + tid * 4);
    float s  = v.x + v.y + v.z + v.w;
    float ss = v.x * v.x + v.y * v.y + v.z * v.z + v.w * v.w;
#pragma unroll
    for (int off = 32; off > 0; off >>= 1) {
      s  += __shfl_xor(s, off);
      ss += __shfl_xor(ss, off);
    }
    __shared__ float rs[4], rss[4];
    const int wid = tid >> 6;
    if ((tid & 63) == 0) { rs[wid] = s; rss[wid] = ss; }
    __syncthreads();
    s  = rs[0] + rs[1] + rs[2] + rs[3];
    ss = rss[0] + rss[1] + rss[2] + rss[3];
    const float mean = s * (1.f / EMB);
    const float var  = ss * (1.f / EMB) - mean * mean;
    const float rstd = rsqrtf(var + 1e-5f);
    float4 gv = *(const float4*)(g1 + tid * 4);
    float4 sv = *(const float4*)(s1 + tid * 4);
    ushort4 o;
    o.x = f2bf((v.x - mean) * rstd * gv.x + sv.x);
    o.y = f2bf((v.y - mean) * rstd * gv.y + sv.y);
    o.z = f2bf((v.z - mean) * rstd * gv.z + sv.z);
    o.w = f2bf((v.w - mean) * rstd * gv.w + sv.w);
    *(ushort4*)(H + (size_t)row * EMB + tid * 4) = o;
    return;
  }

  // ---- weight transpose tile (32n x 64k) ----
  __shared__ float t[64][33];
  const int tx = tid & 31, ty = tid >> 5;
  const float* W; unsigned short* Wt; int K, N, local;
  if (bid < 2048) {
    const int sel = bid >> 9; local = bid & 511; K = 1024; N = 1024;
    W  = sel == 0 ? Wq  : sel == 1 ? Wk  : sel == 2 ? Wv  : Wo;
    Wt = sel == 0 ? wtQ : sel == 1 ? wtK : sel == 2 ? wtV : wtO;
  } else if (bid < 4096) {
    local = bid - 2048; K = 1024; N = 4096; W = W1; Wt = wtW1;
  } else {
    local = bid - 4096; K = 4096; N = 1024; W = W2; Wt = wtW2;
  }
  const int nbx = N >> 5;
  const int n0 = (local % nbx) * 32, k0 = (local / nbx) * 64;
#pragma unroll
  for (int i = 0; i < 8; ++i) {
    const int kr = i * 8 + ty;
    t[kr][tx] = W[(size_t)(k0 + kr) * N + n0 + tx];
  }
  __syncthreads();
#pragma unroll
  for (int i = 0; i < 4; ++i) {
    const int r = ty + i * 8;   // n-row within tile
    const unsigned int u = cvtpk(t[2 * tx][r], t[2 * tx + 1][r]);
    *(unsigned int*)(&Wt[(size_t)(n0 + r) * K + k0 + 2 * tx]) = u;
  }
}

// ---------------------------------------------------------------------------
// LayerNorm: fp32 [rows,1024] -> bf16 [rows,1024].  block 256, grid rows.
// ---------------------------------------------------------------------------
__global__ __launch_bounds__(256) void ln_kernel(
    const float* __restrict__ X, const float* __restrict__ g,
    const float* __restrict__ sh, unsigned short* __restrict__ H)
{
  const int row = blockIdx.x, t = threadIdx.x;
  const float* xr = X + (size_t)row * EMB;
  float4 v = *(const float4*)(xr + t * 4);
  float s  = v.x + v.y + v.z + v.w;
  float ss = v.x * v.x + v.y * v.y + v.z * v.z + v.w * v.w;
#pragma unroll
  for (int off = 32; off > 0; off >>= 1) {
    s  += __shfl_xor(s, off);
    ss += __shfl_xor(ss, off);
  }
  __shared__ float rs[4], rss[4];
  const int wid = t >> 6;
  if ((t & 63) == 0) { rs[wid] = s; rss[wid] = ss; }
  __syncthreads();
  s  = rs[0] + rs[1] + rs[2] + rs[3];
  ss = rss[0] + rss[1] + rss[2] + rss[3];
  const float mean = s * (1.f / EMB);
  const float var  = ss * (1.f / EMB) - mean * mean;
  const float rstd = rsqrtf(var + 1e-5f);
  float4 gv = *(const float4*)(g + t * 4);
  float4 sv = *(const float4*)(sh + t * 4);
  ushort4 o;
  o.x = f2bf((v.x - mean) * rstd * gv.x + sv.x);
  o.y = f2bf((v.y - mean) * rstd * gv.y + sv.y);
  o.z = f2bf((v.z - mean) * rstd * gv.z + sv.z);
  o.w = f2bf((v.w - mean) * rstd * gv.w + sv.w);
  *(ushort4*)(H + (size_t)row * EMB + t * 4) = o;
}

// ---------------------------------------------------------------------------
// 8-phase 256x256 GEMM for W1 (M=N=4096, K=1024): faithful T3+T4 port.
// (See r16 header comment for the slot-recycling schedule proof.)
// ---------------------------------------------------------------------------
__global__ __launch_bounds__(512, 2) void gemm8p(
    const unsigned short* __restrict__ A, const unsigned short* __restrict__ Bt,
    const float* __restrict__ bias, unsigned short* __restrict__ outb)
{
  __shared__ unsigned short As[2][256 * 64];
  __shared__ unsigned short Bs[2][256 * 64];

  const int tid = threadIdx.x;
  const int lane = tid & 63, wid = tid >> 6;
  const int bid = (int)blockIdx.x;
  const int swz = (bid & 7) * 32 + (bid >> 3);   // XCD-chunked, 256 blocks
  const int by = swz >> 4, bx = swz & 15;
  const int m0 = by * 256, n0 = bx * 256;
  const int wr = wid >> 2, wc = wid & 3;
  const int l16 = lane & 15, kg = lane >> 4;

  const int sr  = lane >> 3;                     // 8-row x 64-col 1KB chunks
  const int scs = ((lane & 7) ^ (lane >> 3)) * 8;
  const int rx  = l16 & 7;

  const unsigned short* Ab = A + (size_t)m0 * 1024;
  const unsigned short* Bb = Bt + (size_t)n0 * 1024;

  f32x4 acc[8][4];
#pragma unroll
  for (int i = 0; i < 8; ++i)
#pragma unroll
    for (int j = 0; j < 4; ++j) acc[i][j] = (f32x4){0.f, 0.f, 0.f, 0.f};

#define STGH(ldsdst, gb, grow0, kt_)                                           \
  do {                                                                         \
    _Pragma("unroll")                                                          \
    for (int i_ = 0; i_ < 2; ++i_) {                                           \
      const int c_ = wid * 2 + i_;                                             \
      gl_lds16((gb) + (size_t)((grow0) + c_ * 8 + sr) * 1024 + (kt_) * 64 + scs, \
               (ldsdst) + c_ * 512);                                           \
    }                                                                          \
  } while (0)

#define PHASE(mp, STAGE_STMT, TAIL_STMT)                                       \
  do {                                                                         \
    short8 af[2][2];                                                           \
    _Pragma("unroll")                                                          \
    for (int i = 0; i < 2; ++i)                                                \
      _Pragma("unroll")                                                        \
      for (int kk = 0; kk < 2; ++kk)                                           \
        af[i][kk] = *(const short8*)(                                          \
            &As[b][(wr * 128 + ((mp) * 2 + i) * 16 + l16) * 64 +               \
                   ((kg + kk * 4) ^ rx) * 8]);                                 \
    STAGE_STMT;                                                                \
    __builtin_amdgcn_s_barrier();                                              \
    asm volatile("s_waitcnt lgkmcnt(0)" ::: "memory");                         \
    __builtin_amdgcn_s_setprio(1);                                             \
    _Pragma("unroll")                                                          \
    for (int kk = 0; kk < 2; ++kk)                                             \
      _Pragma("unroll")                                                        \
      for (int j = 0; j < 4; ++j)                                              \
        _Pragma("unroll")                                                      \
        for (int i = 0; i < 2; ++i)                                            \
          acc[(mp) * 2 + i][j] = __builtin_amdgcn_mfma_f32_16x16x32_bf16(      \
              af[i][kk], bf[j][kk], acc[(mp) * 2 + i][j], 0, 0, 0);            \
    __builtin_amdgcn_s_setprio(0);                                             \
    TAIL_STMT;                                                                 \
    __builtin_amdgcn_s_barrier();                                              \
  } while (0)

  STGH(&As[0][0], Ab, 0, 0);   STGH(&As[0][128 * 64], Ab, 128, 0);
  STGH(&Bs[0][0], Bb, 0, 0);   STGH(&Bs[0][128 * 64], Bb, 128, 0);
  STGH(&As[1][0], Ab, 0, 1);   STGH(&As[1][128 * 64], Ab, 128, 1);
  STGH(&Bs[1][0], Bb, 0, 1);   STGH(&Bs[1][128 * 64], Bb, 128, 1);
  asm volatile("s_waitcnt vmcnt(8)" ::: "memory");
  __builtin_amdgcn_s_barrier();

  const int nt = 16;
  for (int t = 0; t < nt; ++t) {
    const int b = t & 1;
    short8 bf[4][2];                 // B fragments for the whole K-tile
#pragma unroll
    for (int j = 0; j < 4; ++j)
#pragma unroll
      for (int kk = 0; kk < 2; ++kk)
        bf[j][kk] = *(const short8*)(
            &Bs[b][(wc * 64 + j * 16 + l16) * 64 + ((kg + kk * 4) ^ rx) * 8]);

    PHASE(0, if (t >= 1 && t + 1 < nt) STGH(&As[b ^ 1][0], Ab, 0, t + 1), );
    PHASE(1, if (t >= 1 && t + 1 < nt) STGH(&As[b ^ 1][128 * 64], Ab, 128, t + 1), );
    PHASE(2, if (t + 2 < nt) STGH(&Bs[b][0], Bb, 0, t + 2), );
    PHASE(3, if (t + 2 < nt) STGH(&Bs[b][128 * 64], Bb, 128, t + 2),
          if (t + 2 < nt) { asm volatile("s_waitcnt vmcnt(4)" ::: "memory"); }
          else            { asm volatile("s_waitcnt vmcnt(0)" ::: "memory"); });
  }
#undef PHASE
#undef STGH

#pragma unroll
  for (int i = 0; i < 8; ++i) {
#pragma unroll
    for (int j = 0; j < 4; ++j) {
      const int c = n0 + wc * 64 + j * 16 + l16;
      const float bc = bias[c];
#pragma unroll
      for (int r = 0; r < 4; ++r) {
        const int row = m0 + wr * 128 + i * 16 + kg * 4 + r;
        outb[(size_t)row * 4096 + c] = f2bf(gelu_tanh_f(acc[i][j][r] + bc));
      }
    }
  }
}

// ---------------------------------------------------------------------------
// GEMM  C[M,N] = A[M,Kld] * Bt[N,Kld]^T  (2-phase counted-vmcnt family)
// ---------------------------------------------------------------------------
template <int MODE, int BN, int BKT, int NBUF>
__global__ __launch_bounds__(256, 2) void gemm_gl(
    const unsigned short* __restrict__ A, const unsigned short* __restrict__ Bt,
    int M, int N, int Kloop, int Kld, int nbx,
    const float* __restrict__ bias, const float* __restrict__ resf,
    float* __restrict__ outf, unsigned short* __restrict__ outb,
    unsigned short* __restrict__ vt)
{
  constexpr int NFRAG = BN / 32;
  constexpr int KK    = BKT / 32;
  constexpr int ACH   = 128 * BKT / 512;
  constexpr int BCH   = BN  * BKT / 512;
  __shared__ unsigned short As[NBUF][128 * BKT];
  __shared__ unsigned short Bs[NBUF][BN * BKT];

  const int tid = threadIdx.x;
  const int lane = tid & 63, wid = tid >> 6;
  const int nwg = (int)gridDim.x;
  const int cpx = nwg >> 3;
  const int bid = (int)blockIdx.x;
  const int swz = (bid & 7) * cpx + (bid >> 3);
  const int by = swz / nbx;
  const int bx = swz - by * nbx;
  const int m0 = by * 128, n0 = bx * BN;
  const int wr = wid >> 1, wc = wid & 1;
  const int l16 = lane & 15, kg = lane >> 4;

  int sr, scs;
  if constexpr (BKT == 32) {
    sr  = lane >> 2;
    scs = ((lane & 3) ^ ((lane >> 3) & 3)) * 8;
  } else {
    sr  = lane >> 3;
    scs = ((lane & 7) ^ (lane >> 3)) * 8;
  }
  const int rx = (BKT == 32) ? ((l16 >> 1) & 3) : (l16 & 7);

  const unsigned short* Abase = A + (size_t)m0 * Kld;
  const unsigned short* Bbase = Bt + (size_t)n0 * Kld;

  f32x4 acc[4][NFRAG];
#pragma unroll
  for (int i = 0; i < 4; ++i)
#pragma unroll
    for (int j = 0; j < NFRAG; ++j) acc[i][j] = (f32x4){0.f, 0.f, 0.f, 0.f};

  const int nt = Kloop / BKT;
  constexpr int RPC = (BKT == 32) ? 16 : 8;

#define STAGE(buf, t)                                                          \
  do {                                                                         \
    const int k0_ = (t) * BKT;                                                 \
    _Pragma("unroll")                                                          \
    for (int i_ = 0; i_ < ACH / 4; ++i_) {                                     \
      const int chunk_ = wid * (ACH / 4) + i_;                                 \
      gl_lds16(Abase + (size_t)(chunk_ * RPC + sr) * Kld + k0_ + scs,          \
               &As[buf][0] + chunk_ * 512);                                    \
    }                                                                          \
    _Pragma("unroll")                                                          \
    for (int i_ = 0; i_ < BCH / 4; ++i_) {                                     \
      const int chunk_ = wid * (BCH / 4) + i_;                                 \
      gl_lds16(Bbase + (size_t)(chunk_ * RPC + sr) * Kld + k0_ + scs,          \
               &Bs[buf][0] + chunk_ * 512);                                    \
    }                                                                          \
  } while (0)

#define VM_WAIT()                                                              \
  do {                                                                         \
    constexpr int W_ = ((ACH + BCH) / 4) * (NBUF - 1);                         \
    if constexpr (W_ == 3)      asm volatile("s_waitcnt vmcnt(3)" ::: "memory"); \
    else if constexpr (W_ == 4) asm volatile("s_waitcnt vmcnt(4)" ::: "memory"); \
    else if constexpr (W_ == 6) asm volatile("s_waitcnt vmcnt(6)" ::: "memory"); \
    else if constexpr (W_ == 8) asm volatile("s_waitcnt vmcnt(8)" ::: "memory"); \
    else                        asm volatile("s_waitcnt vmcnt(12)" ::: "memory"); \
  } while (0)

  STAGE(0, 0);
  STAGE(1, 1);
  if constexpr (NBUF == 3) STAGE(2, 2);
  VM_WAIT();
  __builtin_amdgcn_s_barrier();

  int b = 0;
  for (int t = 0; t < nt; ++t) {
    short8 af[4][KK], bfr[NFRAG][KK];
#pragma unroll
    for (int i = 0; i < 4; ++i)
#pragma unroll
      for (int kk = 0; kk < KK; ++kk)
        af[i][kk] = *(const short8*)(
            &As[b][(wr * 64 + i * 16 + l16) * BKT + ((kg + kk * 4) ^ rx) * 8]);
#pragma unroll
    for (int j = 0; j < NFRAG; ++j)
#pragma unroll
      for (int kk = 0; kk < KK; ++kk)
        bfr[j][kk] = *(const short8*)(
            &Bs[b][(wc * (BN / 2) + j * 16 + l16) * BKT + ((kg + kk * 4) ^ rx) * 8]);
#pragma unroll
    for (int kk = 0; kk < KK; ++kk)
#pragma unroll
      for (int i = 0; i < 4; ++i)
#pragma unroll
        for (int j = 0; j < NFRAG; ++j)
          acc[i][j] = __builtin_amdgcn_mfma_f32_16x16x32_bf16(af[i][kk], bfr[j][kk], acc[i][j], 0, 0, 0);
    asm volatile("s_waitcnt lgkmcnt(0)" ::: "memory");
    __builtin_amdgcn_s_barrier();
    if (t + NBUF < nt) {
      STAGE(b, t + NBUF);
      VM_WAIT();
    } else {
      asm volatile("s_waitcnt vmcnt(0)" ::: "memory");
    }
    __builtin_amdgcn_s_barrier();
    if constexpr (NBUF == 2) b ^= 1;
    else                     b = (b == 2) ? 0 : b + 1;
  }
#undef STAGE
#undef VM_WAIT

#pragma unroll
  for (int i = 0; i < 4; ++i) {
#pragma unroll
    for (int j = 0; j < NFRAG; ++j) {
      const int c = n0 + wc * (BN / 2) + j * 16 + l16;
      if constexpr (MODE == 0) {
        if (c >= 2048) {
          const int row0 = m0 + wr * 64 + i * 16 + kg * 4;
          const int dcol = c - 2048;
          ushort4 w4;
          w4.x = f2bf(acc[i][j][0]); w4.y = f2bf(acc[i][j][1]);
          w4.z = f2bf(acc[i][j][2]); w4.w = f2bf(acc[i][j][3]);
          *(ushort4*)(&vt[((size_t)((row0 >> 11) * 16 + (dcol >> 6)) * 64 +
                           (dcol & 63)) * 2048 + (row0 & 2047)]) = w4;
        } else {
          const float sc = (c < 1024) ? 0.18033688011112042f : 1.0f;
#pragma unroll
          for (int r = 0; r < 4; ++r) {
            const int row = m0 + wr * 64 + i * 16 + kg * 4 + r;
            outb[(size_t)row * QKN + c] = f2bf(acc[i][j][r] * sc);
          }
        }
      } else {
#pragma unroll
        for (int r = 0; r < 4; ++r) {
          const int row = m0 + wr * 64 + i * 16 + kg * 4 + r;
          const size_t idx = (size_t)row * N + c;
          float v = acc[i][j][r];
          if constexpr (MODE == 1) {
            outf[idx] = v + bias[c] + resf[idx];
          } else if constexpr (MODE == 2) {
            outb[idx] = f2bf(gelu_tanh_f(v + bias[c]));
          } else {
            outf[idx] = v + bias[c] + resf[idx];
          }
        }
      }
    }
  }
}

// ---------------------------------------------------------------------------
// MFMA causal flash attention, swapped-operand, pair-balanced, XCD-swizzled,
// KVBLK=128.
// ---------------------------------------------------------------------------
__global__ __launch_bounds__(256) void attn_mfma(
    const unsigned short* __restrict__ qkv, const unsigned short* __restrict__ Vt,
    unsigned short* __restrict__ ctx)
{
  __shared__ unsigned short Ks[128][64];
  __shared__ unsigned short Vs[64][128];   // [d][key]
  __shared__ unsigned short Ps[4][2][16][128];

  const int tid  = threadIdx.x;
  const int lane = tid & 63, wv = tid >> 6;
  const int l16  = lane & 15, kg = lane >> 4;
  const int bid  = (int)blockIdx.x;
  const int swz  = (bid & 7) * 64 + (bid >> 3);
  const int pair = swz & 15;
  const int bh   = swz >> 4;
  const int b    = bh >> 4, h = bh & 15;
  const int qtg0 = pair;        // light q-tile (64 rows)
  const int qtg1 = 31 - pair;   // heavy q-tile

  const size_t qbase  = ((size_t)b * S_LEN) * QKN + h * HDIM;
  const size_t kbase  = qbase + 1024;
  const size_t vtbase = ((size_t)bh * HDIM) * S_LEN;
  const size_t cbase  = ((size_t)b * S_LEN) * EMB + h * HDIM;

  short8 qf[2][2];
#pragma unroll
  for (int g = 0; g < 2; ++g) {
    const int qt = g ? qtg1 : qtg0;
    const unsigned short* qrow =
        qkv + qbase + (size_t)(qt * 64 + wv * 16 + l16) * QKN;
    qf[g][0] = *(const short8*)(qrow + kg * 8);
    qf[g][1] = *(const short8*)(qrow + 32 + kg * 8);
  }

  f32x4 o[2][4];
#pragma unroll
  for (int g = 0; g < 2; ++g)
#pragma unroll
    for (int dt = 0; dt < 4; ++dt) o[g][dt] = (f32x4){0.f, 0.f, 0.f, 0.f};
  float m[2] = {-1e30f, -1e30f}, l[2] = {0.f, 0.f};

  const int kr2 = tid >> 1, kh = tid & 1;
  const int ksx = kr2 & 7;
  const int vr = tid >> 2, vc = tid & 3;
  const int vsx = vr & 7;
  const int rx = l16 & 7;

  const int nkt = (qtg1 + 2) >> 1;

  const unsigned short* ksrc = qkv + kbase + (size_t)kr2 * QKN + kh * 32;
  const unsigned short* vsrc = Vt + vtbase + (size_t)vr * S_LEN + vc * 32;
  short8 kv0 = *(const short8*)(ksrc);
  short8 kv1 = *(const short8*)(ksrc + 8);
  short8 kv2 = *(const short8*)(ksrc + 16);
  short8 kv3 = *(const short8*)(ksrc + 24);
  short8 vv0 = *(const short8*)(vsrc);
  short8 vv1 = *(const short8*)(vsrc + 8);
  short8 vv2 = *(const short8*)(vsrc + 16);
  short8 vv3 = *(const short8*)(vsrc + 24);

  for (int kt = 0; kt < nkt; ++kt) {
    __syncthreads();
    *(short8*)(&Ks[kr2][((kh * 4 + 0) ^ ksx) * 8]) = kv0;
    *(short8*)(&Ks[kr2][((kh * 4 + 1) ^ ksx) * 8]) = kv1;
    *(short8*)(&Ks[kr2][((kh * 4 + 2) ^ ksx) * 8]) = kv2;
    *(short8*)(&Ks[kr2][((kh * 4 + 3) ^ ksx) * 8]) = kv3;
    *(short8*)(&Vs[vr][((vc * 4 + 0) ^ vsx) * 8]) = vv0;
    *(short8*)(&Vs[vr][((vc * 4 + 1) ^ vsx) * 8]) = vv1;
    *(short8*)(&Vs[vr][((vc * 4 + 2) ^ vsx) * 8]) = vv2;
    *(short8*)(&Vs[vr][((vc * 4 + 3) ^ vsx) * 8]) = vv3;
    __syncthreads();

    if (kt + 1 < nkt) {
      const unsigned short* kn =
          qkv + kbase + (size_t)((kt + 1) * 128 + kr2) * QKN + kh * 32;
      const unsigned short* vn =
          Vt + vtbase + (size_t)vr * S_LEN + (kt + 1) * 128 + vc * 32;
      kv0 = *(const short8*)(kn);
      kv1 = *(const short8*)(kn + 8);
      kv2 = *(const short8*)(kn + 16);
      kv3 = *(const short8*)(kn + 24);
      vv0 = *(const short8*)(vn);
      vv1 = *(const short8*)(vn + 8);
      vv2 = *(const short8*)(vn + 16);
      vv3 = *(const short8*)(vn + 24);
    }

    const bool act0 = (2 * kt <= qtg0);

    float fac[2] = {1.f, 1.f};
    bool resc[2] = {false, false};
#pragma unroll
    for (int g = 0; g < 2; ++g) {
      if (g == 0 && !act0) continue;
      const int qt = g ? qtg1 : qtg0;

      f32x4 sa[8];
      __builtin_amdgcn_s_setprio(1);
#pragma unroll
      for (int j = 0; j < 8; ++j) {
        short8 kf0 = *(const short8*)(&Ks[j * 16 + l16][(kg ^ rx) * 8]);
        short8 kf1 = *(const short8*)(&Ks[j * 16 + l16][((kg + 4) ^ rx) * 8]);
        sa[j] = (f32x4){0.f, 0.f, 0.f, 0.f};
        sa[j] = __builtin_amdgcn_mfma_f32_16x16x32_bf16(kf0, qf[g][0], sa[j], 0, 0, 0);
        sa[j] = __builtin_amdgcn_mfma_f32_16x16x32_bf16(kf1, qf[g][1], sa[j], 0, 0, 0);
      }
      __builtin_amdgcn_s_setprio(0);

      const int qloc = qt * 64 + wv * 16 + l16;
      if (kt * 128 + 127 > qt * 64 + wv * 16) {
#pragma unroll
        for (int j = 0; j < 8; ++j)
#pragma unroll
          for (int r = 0; r < 4; ++r)
            if (kt * 128 + j * 16 + kg * 4 + r > qloc) sa[j][r] = -1e30f;
      }

      float mx = fmaxf(fmaxf(sa[0][0], sa[0][1]), fmaxf(sa[0][2], sa[0][3]));
#pragma unroll
      for (int j = 1; j < 8; ++j) {
        float mj = fmaxf(fmaxf(sa[j][0], sa[j][1]), fmaxf(sa[j][2], sa[j][3]));
        mx = fmaxf(mx, mj);
      }
      mx = fmaxf(mx, __shfl_xor(mx, 16));
      mx = fmaxf(mx, __shfl_xor(mx, 32));
      if (!__all(mx - m[g] <= 8.0f)) {
        const float mn = fmaxf(m[g], mx);
        fac[g] = exp2f(m[g] - mn);
        m[g] = mn;
        resc[g] = true;
      }
      const float mcur = m[g];
      float ps = 0.f;
#pragma unroll
      for (int j = 0; j < 8; ++j) {
        float p0 = exp2f(sa[j][0] - mcur);
        float p1 = exp2f(sa[j][1] - mcur);
        float p2 = exp2f(sa[j][2] - mcur);
        float p3 = exp2f(sa[j][3] - mcur);
        sa[j][0] = p0; sa[j][1] = p1; sa[j][2] = p2; sa[j][3] = p3;
        ps += (p0 + p1) + (p2 + p3);
      }
      ps += __shfl_xor(ps, 16);
      ps += __shfl_xor(ps, 32);
      l[g] = l[g] * fac[g] + ps;

#pragma unroll
      for (int j = 0; j < 8; ++j) {
        uint2 pw;
        pw.x = cvtpk(sa[j][0], sa[j][1]);
        pw.y = cvtpk(sa[j][2], sa[j][3]);
        *(uint2*)(&Ps[wv][g][l16][((2 * j + (kg >> 1)) ^ rx) * 8 + (kg & 1) * 4]) = pw;
      }
    }

#pragma unroll
    for (int g = 0; g < 2; ++g) {
      if (resc[g]) {
#pragma unroll
        for (int dt = 0; dt < 4; ++dt)
#pragma unroll
          for (int r = 0; r < 4; ++r) o[g][dt][r] *= fac[g];
      }
    }

    short8 pf[2][4];
#pragma unroll
    for (int g = 0; g < 2; ++g) {
      if (g == 0 && !act0) continue;
#pragma unroll
      for (int s = 0; s < 4; ++s)
        pf[g][s] = *(const short8*)(&Ps[wv][g][l16][((4 * s + kg) ^ rx) * 8]);
    }
    __builtin_amdgcn_s_setprio(1);
#pragma unroll
    for (int dt = 0; dt < 4; ++dt) {
#pragma unroll
      for (int s = 0; s < 4; ++s) {
        short8 vf = *(const short8*)(&Vs[dt * 16 + l16][((4 * s + kg) ^ rx) * 8]);
#pragma unroll
        for (int g = 0; g < 2; ++g) {
          if (g == 0 && !act0) continue;
          o[g][dt] = __builtin_amdgcn_mfma_f32_16x16x32_bf16(vf, pf[g][s], o[g][dt], 0, 0, 0);
        }
      }
    }
    __builtin_amdgcn_s_setprio(0);
  }

#pragma unroll
  for (int g = 0; g < 2; ++g) {
    const int qt = g ? qtg1 : qtg0;
    const float inv = 1.0f / l[g];
    const int qrow = qt * 64 + wv * 16 + l16;
#pragma unroll
    for (int dt = 0; dt < 4; ++dt) {
      uint2 cw;
      cw.x = cvtpk(o[g][dt][0] * inv, o[g][dt][1] * inv);
      cw.y = cvtpk(o[g][dt][2] * inv, o[g][dt][3] * inv);
      *(uint2*)(&ctx[cbase + (size_t)qrow * EMB + dt * 16 + kg * 4]) = cw;
    }
  }
}

// ---------------------------------------------------------------------------
// ws layout (MB): 0-2 wtQ | 2-4 wtK | 4-6 wtV | 6-8 wtO | 8-16 wtW1 |
//   16-24 wtW2 | 24-32 h/ctx/h2 | 32-48 qkv | 56-64 Vt | 32-64 gbuf
// ---------------------------------------------------------------------------
extern "C" void kernel_launch(void* const* d_in, const int* in_sizes, int n_in,
                              void* d_out, int out_size, void* d_ws, size_t ws_size,
                              hipStream_t stream)
{
  const float* x  = (const float*)d_in[0];
  const float* Wq = (const float*)d_in[1];
  const float* Wk = (const float*)d_in[2];
  const float* Wv = (const float*)d_in[3];
  const float* Wo = (const float*)d_in[4];
  const float* bo = (const float*)d_in[5];
  const float* W1 = (const float*)d_in[6];
  const float* b1 = (const float*)d_in[7];
  const float* W2 = (const float*)d_in[8];
  const float* b2 = (const float*)d_in[9];
  const float* g1 = (const float*)d_in[10];
  const float* s1 = (const float*)d_in[11];
  const float* g2 = (const float*)d_in[12];
  const float* s2 = (const float*)d_in[13];

  float* out = (float*)d_out;
  char* ws = (char*)d_ws;
  const size_t MB = 1024 * 1024;
  unsigned short* wtQ  = (unsigned short*)(ws + 0 * MB);
  unsigned short* wtK  = (unsigned short*)(ws + 2 * MB);
  unsigned short* wtV  = (unsigned short*)(ws + 4 * MB);
  unsigned short* wtO  = (unsigned short*)(ws + 6 * MB);
  unsigned short* wtW1 = (unsigned short*)(ws + 8 * MB);
  unsigned short* wtW2 = (unsigned short*)(ws + 16 * MB);
  unsigned short* h    = (unsigned short*)(ws + 24 * MB);
  unsigned short* qkv  = (unsigned short*)(ws + 32 * MB);
  unsigned short* Vt   = (unsigned short*)(ws + 56 * MB);
  unsigned short* ctxb = h;
  unsigned short* h2   = h;
  unsigned short* gbuf = qkv;            // reuse 32..64MB after attn

  // fused: weight transposes + LN1 (one launch)
  prep_kernel<<<dim3(10240), 256, 0, stream>>>(
      Wq, Wk, Wv, Wo, W1, W2, wtQ, wtK, wtV, wtO, wtW1, wtW2, x, g1, s1, h);

  // fused QKV: Q (pre-scaled), K -> qkv[4096,2048]; V -> Vt transposed
  gemm_gl<0, 128, 32, 2><<<dim3(24 * 32), 256, 0, stream>>>(
      h, wtQ, MTOT, 3072, 1024, 1024, 24, nullptr, nullptr, nullptr, qkv, Vt);

  attn_mfma<<<dim3(512), 256, 0, stream>>>(qkv, Vt, ctxb);

  // x_attn = x + ctx@Wo + bo.  512 blocks (2/CU), BKT=64, NBUF=2.
  gemm_gl<1, 64, 64, 2><<<dim3(16 * 32), 256, 0, stream>>>(
      ctxb, wtO, MTOT, 1024, 1024, 1024, 16, bo, x, out, nullptr, nullptr);

  ln_kernel<<<MTOT, 256, 0, stream>>>(out, g2, s2, h2);

  // W1: 8-phase 256x256 (T3+T4 faithful port), 256 blocks, 8 waves.
  gemm8p<<<dim3(256), 512, 0, stream>>>(h2, wtW1, b1, gbuf);

  // out = x_attn + gbuf@W2 + b2.  512 blocks (2/CU), BKT=64, NBUF=2.
  gemm_gl<3, 64, 64, 2><<<dim3(16 * 32), 256, 0, stream>>>(
      gbuf, wtW2, MTOT, 1024, DFF, DFF, 16, b2, out, out, nullptr, nullptr);
}